// Round 11
// baseline (293.366 us; speedup 1.0000x reference)
//
#include <hip/hip_runtime.h>
#include <hip/hip_bf16.h>

#define CIN   64
#define COUT  64
#define TT    512
#define FF    161
#define KTOT  576          // 9 * 64
#define WST   (COUT*KTOT)  // 36864 shorts per f
#define TFSTR (TT*FF)      // 82432
#define FP_   168          // padded f dim of X2: fp = f+1, zeros at fp=0 and fp>=162

#define W2_BYTES  ((size_t)FF*COUT*KTOT*2)           // 11,870,208
#define X2_BYTES  ((size_t)8*TT*FP_*64*2)            // 88,080,384
#define TMP_BYTES ((size_t)8*FF*TT*COUT*2)           // 84,410,368
#define PREPW_BLOCKS 512

typedef __bf16 bf16x8 __attribute__((ext_vector_type(8)));
typedef float  f32x4  __attribute__((ext_vector_type(4)));
typedef float  f32x16 __attribute__((ext_vector_type(16)));
typedef unsigned short u16x8 __attribute__((ext_vector_type(8)));
typedef unsigned short u16x4 __attribute__((ext_vector_type(4)));
typedef unsigned int   u32x2 __attribute__((ext_vector_type(2)));
typedef float f4u __attribute__((ext_vector_type(4), aligned(4)));

__device__ __forceinline__ unsigned short f2bf(float v) {
    union { float f; unsigned int u; } c; c.f = v;
    unsigned int u = c.u + 0x7FFFu + ((c.u >> 16) & 1u);   // RNE
    return (unsigned short)(u >> 16);
}
__device__ __forceinline__ float bf2f(unsigned short h) {
    union { unsigned int u; float f; } c; c.u = (unsigned)h << 16;
    return c.f;
}

// ---- fused prep v2 ----
// blocks [0,512): weight repack, coalesced BOTH sides via LDS transpose.
//   block = (o, f-chunk): read 64 i-rows of nf*9 CONSECUTIVE dwords (stride
//   FF*9 between rows); write per (f): contiguous k-rows of W2[f][o][k].
// blocks [512, 512+4096): x transpose (unchanged from round 7).
__global__ __launch_bounds__(256) void prep_fused2(
    const float* __restrict__ ksrc, unsigned short* __restrict__ w2,
    const float* __restrict__ x, unsigned short* __restrict__ x2)
{
    __shared__ unsigned short Ls[64*190];       // 24,320 B (weight path)
    __shared__ unsigned short Xs[64][172];      // 22,016 B (x path)
    int bx = blockIdx.x;
    int tid = threadIdx.x;

    if (bx < PREPW_BLOCKS) {
        int o  = bx >> 3;
        int c  = bx & 7;
        int f0 = c * 21;
        int nf = (c == 7) ? 14 : 21;            // 7*21 + 14 = 161
        int nr = nf * 9;                        // <= 189
        const float* src = ksrc + (size_t)o*64*FF*9 + f0*9;
        int tot = 64 * nr;
        for (int e = tid; e < tot; e += 256) {  // consecutive e -> consecutive dwords
            int i  = e / nr;
            int rr = e - i*nr;
            Ls[i*190 + rr] = f2bf(src[(size_t)i*FF*9 + rr]);
        }
        __syncthreads();
        unsigned short* dst = w2 + (size_t)f0*WST + o*KTOT;
        int wt = nf * 144;                      // (fl, q, i/4)
        for (int w = tid; w < wt; w += 256) {
            int fl = w / 144;
            int rr = w - fl*144;
            int q  = rr >> 4;
            int i0 = (rr & 15) * 4;
            u16x4 v;
            #pragma unroll
            for (int e = 0; e < 4; ++e) v[e] = Ls[(i0 + e)*190 + fl*9 + q];
            *(u16x4*)&dst[(size_t)fl*WST + q*64 + i0] = v;   // 8B coalesced
        }
        return;
    }

    // x: (b,i,t,f) f32 -> X2[b][t][fp][i] bf16, fp=f+1 (zero-padded halo cols)
    int bt = bx - PREPW_BLOCKS;                 // 0..4095
    int b  = bt >> 9;
    int t  = bt & 511;
    const float* xb = x + (size_t)b*CIN*TFSTR + (size_t)t*FF;
    #pragma unroll
    for (int k = 0; k < 11; ++k) {
        int s = tid + k*256;
        if (s < 2624) {                         // 64 i * 41 slots
            int i = s / 41;
            int u = s - i*41;
            const float* p = xb + (size_t)i*TFSTR + 4*u;
            if (u < 40) {
                f4u v = *(const f4u*)p;
                u32x2 pk = { (unsigned)f2bf(v.x) | ((unsigned)f2bf(v.y) << 16),
                             (unsigned)f2bf(v.z) | ((unsigned)f2bf(v.w) << 16) };
                *(u32x2*)&Xs[i][4*u] = pk;      // 344B rows: 8B aligned
            } else {
                Xs[i][160] = f2bf(*p);
            }
        }
    }
    __syncthreads();
    unsigned short* ob = x2 + (size_t)bt * FP_ * 64;
    #pragma unroll
    for (int k = 0; k < 6; ++k) {
        int s = tid + k*256;
        if (s < 1344) {                         // 168 fp rows * 8 chunks
            int fp = s >> 3;
            int j  = s & 7;
            u16x8 v = {0,0,0,0,0,0,0,0};
            if (fp >= 1 && fp < 162) {
                int f = fp - 1;
                #pragma unroll
                for (int e = 0; e < 8; ++e) v[e] = Xs[j*8 + e][f];
            }
            *(u16x8*)&ob[fp*64 + j*8] = v;
        }
    }
}

// ---- conv: r9 vehicle (2f x 64o x 64t, one-shot, 33.8KB LDS, 4 blk/CU) but
// 32x32x16 MFMA: wave = (f, o-half-32), 2 m-frags x 36 k-steps.
// Per wave: 72 MFMA + 72 ds_read_b128 + 36 weight loads (was 144+96+36).
__global__ __launch_bounds__(256, 4) void conv_mfma10(
    const unsigned short* __restrict__ x2, const unsigned short* __restrict__ w2,
    const float* __restrict__ bias, unsigned short* __restrict__ tmp)
{
    int bx   = blockIdx.x;          // 5184 = 8 xcd * 81 fblk * 8 tq
    int b    = bx & 7;              // XCD = batch
    int r    = bx >> 3;             // fblk-outer, tq-inner: weight window L2-hot
    int tq   = r & 7;
    int fblk = r >> 3;              // 0..80
    int t0   = tq * 64;
    int f0   = fblk * 2;

    // LDS rows = fl*66 + tl (fl 0..3, tl 0..65), 64 bf16 (128B, 8x16B slots)
    __shared__ alignas(16) unsigned short As[264*64];   // 33,792 B

    int tid = threadIdx.x;
    int wq  = tid >> 6;
    int l   = tid & 63;
    int l31 = l & 31;
    int lh  = l >> 5;               // k-half (documented A/B k split)
    int f   = f0 + (wq >> 1);       // wave's frequency
    int o   = (wq & 1)*32 + l31;    // wave's o-half + lane col
    int flb = wq >> 1;              // f - f0

    const unsigned short* zrow = x2 + 167*64;   // guaranteed-zero row

    // ---- stage whole tile (identical to r9's proven pattern) ----
    #pragma unroll
    for (int it = 0; it < 9; ++it) {
        int idx = tid + it*256;
        if (idx < 2112) {           // 264 rows x 8 slots of 16B
            int row = idx >> 3;
            int j   = idx & 7;
            int fl  = row / 66;
            int tl  = row - fl*66;
            int gt  = t0 - 1 + tl;
            int fp  = f0 + fl;      // <= 163 < FP_
            bool ok = (gt >= 0) && (gt < TT);
            int key = (tl + fl) & 7;
            const unsigned short* src = ok
                ? x2 + ((((size_t)b*TT + gt)*FP_ + fp)*64 + ((j ^ key) * 8))
                : zrow + j*8;
            __builtin_amdgcn_global_load_lds(
                (const __attribute__((address_space(1))) void*)src,
                (__attribute__((address_space(3))) void*)(As + (size_t)idx*8),
                16, 0, 0);
        }
    }
    __syncthreads();

    f32x16 acc0 = {}, acc1 = {};
    // weight row for (f,o), k-half offset baked in
    const unsigned short* wb = w2 + ((size_t)f*COUT + o)*KTOT + lh*8;
    // (fblk==80, wq>=2: f=161 reads run past w2 into x2 region of d_ws: safe, discarded)

    bf16x8 bwA[4], bwB[4];
    auto ldw = [&](bf16x8 (&dst)[4], int t9) {  // t9 constant under full unroll
        #pragma unroll
        for (int ks = 0; ks < 4; ++ks)
            dst[ks] = *(const bf16x8*)&wb[t9*64 + ks*16];
    };

    ldw(bwA, 0);
    #pragma unroll
    for (int t9 = 0; t9 < 9; ++t9) {
        if (t9 < 8) { if (t9 & 1) ldw(bwA, t9 + 1); else ldw(bwB, t9 + 1); }
        int dm = t9 / 3, dn = t9 - dm*3;
        int fl = flb + dn;                      // 0..3
        #pragma unroll
        for (int ks = 0; ks < 4; ++ks) {
            int sb = ks*2 + lh;                 // 16B slot base (k-window)
            int tlA = l31 + dm;
            int slA = sb ^ ((tlA + fl) & 7);
            bf16x8 a0 = *(const bf16x8*)&As[(size_t)(fl*66 + tlA)*64 + slA*8];
            int tlB = 32 + l31 + dm;
            int slB = sb ^ ((tlB + fl) & 7);
            bf16x8 a1 = *(const bf16x8*)&As[(size_t)(fl*66 + tlB)*64 + slB*8];
            bf16x8 bw = (t9 & 1) ? bwB[ks] : bwA[ks];
            acc0 = __builtin_amdgcn_mfma_f32_32x32x16_bf16(a0, bw, acc0, 0, 0, 0);
            acc1 = __builtin_amdgcn_mfma_f32_32x32x16_bf16(a1, bw, acc1, 0, 0, 0);
        }
    }

    // ---- epilogue: bias + bf16 -> tmp[b][f][t][o] ----
    if (f < FF) {                   // per-wave guard; no barriers below
        float bv = bias[o*FF + f];
        size_t tb = ((size_t)b*FF + f)*TT + t0;
        #pragma unroll
        for (int reg = 0; reg < 16; ++reg) {
            int t = (reg & 3) + 8*(reg >> 2) + 4*lh;    // C/D row [m74/m101]
            tmp[(tb + t)*COUT + o]      = f2bf(acc0[reg] + bv);
            tmp[(tb + t + 32)*COUT + o] = f2bf(acc1[reg] + bv);
        }
    }
}

// ---- finalize: tmp[b][f][t][o] bf16 -> out[b][o][t][f] f32 (bias already in) ----
__global__ __launch_bounds__(256) void finalize2(
    const unsigned short* __restrict__ tmp, float* __restrict__ out)
{
    int bx = blockIdx.x;            // 2048
    int b  = bx & 7;
    int s  = bx >> 3;
    int tb = s >> 1;
    int oh = s & 1;
    int t0 = tb * 4;
    int o0 = oh * 32;

    __shared__ unsigned short Ld[644*40];       // 51,520 B

    int tid = threadIdx.x;

    #pragma unroll
    for (int k = 0; k < 11; ++k) {
        int sl = tid + k*256;
        if (sl < 2576) {            // 161 f x 4 t x 4 j
            int f = sl >> 4;
            int r = sl & 15;
            int t = r >> 2;
            int j = r & 3;
            const unsigned short* src =
                tmp + (((size_t)b*FF + f)*TT + t0 + t)*COUT + o0 + j*8;
            int row = t*FF + f;
            *(u16x8*)&Ld[row*40 + ((j ^ (f & 3)) << 3)] = *(const u16x8*)src;
        }
    }
    __syncthreads();

    for (int ol = 0; ol < 32; ++ol) {
        int o = o0 + ol;
        float* op = out + (((size_t)b*COUT + o)*TT + t0)*FF;
        int jo = ol >> 3, o7 = ol & 7;
        #pragma unroll
        for (int k = 0; k < 3; ++k) {
            int r = tid + k*256;
            if (r < 4*FF) {
                int f = r % FF;
                op[r] = bf2f(Ld[r*40 + ((jo ^ (f & 3)) << 3) + o7]);
            }
        }
    }
}

// ---- small fallback: stages directly from f32 x; needs only w2 (12 MB ws) ----
__global__ __launch_bounds__(256) void conv_mfma(
    const float* __restrict__ x, const unsigned short* __restrict__ w2,
    const float* __restrict__ bias, float* __restrict__ out)
{
    int bx = blockIdx.x;
    int r  = bx & 7;
    int q  = bx >> 3;
    int fblk = q % 41;
    int g  = (q / 41) * 8 + r;
    int b  = g >> 3;
    int t0 = (g & 7) * 64;
    int f0 = fblk * 4;

    __shared__ unsigned short Bs[6][66][64];
    int tid = threadIdx.x;

    for (int i = 0; i < 64; i += 4) {
        #pragma unroll
        for (int pp = 0; pp < 2; ++pp) {
            int p = tid + pp*256;
            if (p < 396) {
                int tl = p / 6, fl = p % 6;
                int gt = t0 - 1 + tl;
                int gf = f0 - 1 + fl;
                bool ok = (gt >= 0) && (gt < TT) && (gf >= 0) && (gf < FF);
                const float* xp = x + (((size_t)(b*CIN + i)*TT + gt)*FF + gf);
                float v0 = ok ? xp[0]       : 0.f;
                float v1 = ok ? xp[TFSTR]   : 0.f;
                float v2 = ok ? xp[2*TFSTR] : 0.f;
                float v3 = ok ? xp[3*TFSTR] : 0.f;
                int isw = i ^ (((tl + fl) & 7) << 3);
                ushort4 pk;
                pk.x = f2bf(v0); pk.y = f2bf(v1); pk.z = f2bf(v2); pk.w = f2bf(v3);
                *reinterpret_cast<ushort4*>(&Bs[fl][tl][isw]) = pk;
            }
        }
    }
    __syncthreads();

    int wv = tid >> 6;
    int l  = tid & 63;
    int f  = f0 + wv;
    if (f >= FF) return;

    int l15 = l & 15;
    int lq  = l >> 4;
    f32x4 acc[4][4] = {};
    const unsigned short* wb = w2 + (size_t)f * (COUT * KTOT);

    #pragma unroll
    for (int dm = 0; dm < 3; ++dm)
    #pragma unroll
    for (int dn = 0; dn < 3; ++dn) {
        int fl = wv + dn;
        int kq = (dm*3 + dn) * 64;
        #pragma unroll
        for (int is = 0; is < 2; ++is) {
            int i0 = is*32 + lq*8;
            bf16x8 a[4];
            #pragma unroll
            for (int mf = 0; mf < 4; ++mf) {
                int tl  = mf*16 + l15 + dm;
                int isw = i0 ^ (((tl + fl) & 7) << 3);
                a[mf] = *(const bf16x8*)&Bs[fl][tl][isw];
            }
            int kb = kq + i0;
            #pragma unroll
            for (int nf = 0; nf < 4; ++nf) {
                bf16x8 bfr = *(const bf16x8*)&wb[(size_t)(nf*16 + l15) * KTOT + kb];
                #pragma unroll
                for (int mf = 0; mf < 4; ++mf)
                    acc[mf][nf] = __builtin_amdgcn_mfma_f32_16x16x32_bf16(
                        a[mf], bfr, acc[mf][nf], 0, 0, 0);
            }
        }
    }

    #pragma unroll
    for (int nf = 0; nf < 4; ++nf) {
        int o = nf*16 + l15;
        float bv = bias[o*FF + f];
        size_t obase = (((size_t)b*COUT + o)*TT + t0 + lq*4)*FF + f;
        #pragma unroll
        for (int mf = 0; mf < 4; ++mf)
            #pragma unroll
            for (int rr = 0; rr < 4; ++rr)
                out[obase + (size_t)(mf*16 + rr)*FF] = acc[mf][nf][rr] + bv;
    }
}

extern "C" void kernel_launch(void* const* d_in, const int* in_sizes, int n_in,
                              void* d_out, int out_size, void* d_ws, size_t ws_size,
                              hipStream_t stream)
{
    (void)in_sizes; (void)n_in; (void)out_size;
    const float* x    = (const float*)d_in[0];
    const float* k    = (const float*)d_in[1];
    const float* bias = (const float*)d_in[2];
    float* out = (float*)d_out;
    unsigned short* w2  = (unsigned short*)d_ws;
    unsigned short* x2  = (unsigned short*)((char*)d_ws + W2_BYTES);
    unsigned short* tmp = (unsigned short*)((char*)d_ws + W2_BYTES + X2_BYTES);

    bool big2 = (ws_size >= W2_BYTES + X2_BYTES + TMP_BYTES);

    if (big2) {
        prep_fused2<<<PREPW_BLOCKS + 8*TT, 256, 0, stream>>>(k, w2, x, x2);
        conv_mfma10<<<5184, 256, 0, stream>>>(x2, w2, bias, tmp);  // 4 blocks/CU
        finalize2<<<2048, 256, 0, stream>>>(tmp, out);
    } else {
        prep_fused2<<<PREPW_BLOCKS, 256, 0, stream>>>(k, w2, x, x2);
        conv_mfma<<<8*41*8, 256, 0, stream>>>(x, w2, bias, out);   // fallback
    }
}

// Round 12
// 264.771 us; speedup vs baseline: 1.1080x; 1.1080x over previous
//
#include <hip/hip_runtime.h>
#include <hip/hip_bf16.h>

#define CIN   64
#define COUT  64
#define TT    512
#define FF    161
#define KTOT  576          // 9 * 64
#define WST   (COUT*KTOT)  // 36864 shorts per f
#define TFSTR (TT*FF)      // 82432
#define FP_   168          // padded f dim of X2: fp = f+1, zeros at fp=0 and fp>=162

#define W2_BYTES  ((size_t)FF*COUT*KTOT*2)           // 11,870,208
#define X2_BYTES  ((size_t)8*TT*FP_*64*2)            // 88,080,384
#define TMP_BYTES ((size_t)8*FF*TT*COUT*2)           // 84,410,368
#define PW_BLOCKS 5796                               // 161*9216/256 u16x4 quads

typedef __bf16 bf16x8 __attribute__((ext_vector_type(8)));
typedef float  f32x4  __attribute__((ext_vector_type(4)));
typedef unsigned short u16x8 __attribute__((ext_vector_type(8)));
typedef unsigned short u16x4 __attribute__((ext_vector_type(4)));
typedef unsigned int   u32x2 __attribute__((ext_vector_type(2)));
typedef float f4u __attribute__((ext_vector_type(4), aligned(4)));
typedef float f2u __attribute__((ext_vector_type(2), aligned(4)));

__device__ __forceinline__ unsigned short f2bf(float v) {
    union { float f; unsigned int u; } c; c.f = v;
    unsigned int u = c.u + 0x7FFFu + ((c.u >> 16) & 1u);   // RNE
    return (unsigned short)(u >> 16);
}
__device__ __forceinline__ float bf2f(unsigned short h) {
    union { unsigned int u; float f; } c; c.u = (unsigned)h << 16;
    return c.f;
}

// ---- fused prep (r7 version — fastest measured): weights + x transpose ----
__global__ __launch_bounds__(256) void prep_fused(
    const float* __restrict__ ksrc, unsigned short* __restrict__ w2,
    const float* __restrict__ x, unsigned short* __restrict__ x2)
{
    __shared__ unsigned short Xs[64][172];      // 22,016 B
    int bx = blockIdx.x;
    int tid = threadIdx.x;

    if (bx < PW_BLOCKS) {                       // W2[f][o][k], k=(kh*3+kw)*64+i
        int g  = bx*256 + tid;
        int f  = g / 9216;
        int j  = g - f*9216;
        int o  = j / 144;
        int r  = j - o*144;
        int q  = r >> 4;
        int i4 = (r & 15) * 4;
        u16x4 v;
        #pragma unroll
        for (int e = 0; e < 4; ++e)
            v[e] = f2bf(ksrc[((size_t)(o*64 + i4 + e)*FF + f)*9 + q]);
        *(u16x4*)&w2[(size_t)f*36864 + j*4] = v;
        return;
    }

    int bt = bx - PW_BLOCKS;                    // 0..4095
    int b  = bt >> 9;
    int t  = bt & 511;
    const float* xb = x + (size_t)b*CIN*TFSTR + (size_t)t*FF;
    #pragma unroll
    for (int k = 0; k < 11; ++k) {
        int s = tid + k*256;
        if (s < 2624) {                         // 64 i * 41 slots
            int i = s / 41;
            int u = s - i*41;
            const float* p = xb + (size_t)i*TFSTR + 4*u;
            if (u < 40) {
                f4u v = *(const f4u*)p;
                u32x2 pk = { (unsigned)f2bf(v.x) | ((unsigned)f2bf(v.y) << 16),
                             (unsigned)f2bf(v.z) | ((unsigned)f2bf(v.w) << 16) };
                *(u32x2*)&Xs[i][4*u] = pk;
            } else {
                Xs[i][160] = f2bf(*p);
            }
        }
    }
    __syncthreads();
    unsigned short* ob = x2 + (size_t)bt * FP_ * 64;
    #pragma unroll
    for (int k = 0; k < 6; ++k) {
        int s = tid + k*256;
        if (s < 1344) {                         // 168 fp rows * 8 chunks
            int fp = s >> 3;
            int j  = s & 7;
            u16x8 v = {0,0,0,0,0,0,0,0};
            if (fp >= 1 && fp < 162) {
                int f = fp - 1;
                #pragma unroll
                for (int e = 0; e < 8; ++e) v[e] = Xs[j*8 + e][f];
            }
            *(u16x8*)&ob[fp*64 + j*8] = v;
        }
    }
}

// ---- conv: fp-RING pipelined f-loop on the r9 (conflict-free 16x16) inner loop.
// Block = 2f-per-iter x 64o x 64t, loops 2-3 fblk. LDS = 6-plane ring (50.7 KB,
// 3 blk/CU). Per iter: stage 2 NEW planes BEFORE compute; one barrier AFTER the
// epilogue -> drain covered by compute; x2 read once (no r10 FETCH thrash).
__global__ __launch_bounds__(256, 3) void conv_mfma11(
    const unsigned short* __restrict__ x2, const unsigned short* __restrict__ w2,
    const float* __restrict__ bias, unsigned short* __restrict__ tmp)
{
    int bx  = blockIdx.x;           // 2048 = 8 xcd * 8 tq * 32 seg
    int b   = bx & 7;               // XCD = batch
    int s   = bx >> 3;              // tq-inner: same-seg blocks share weight stream
    int tq  = s & 7;
    int seg = s >> 3;               // 0..31
    int fb0   = (seg < 17) ? seg*3 : 51 + (seg - 17)*2;   // 17x3 + 15x2 = 81
    int niter = (seg < 17) ? 3 : 2;
    int t0  = tq * 64;

    // ring: plane p (fp) lives at slot fp%6; plane = 66 rows x 64 shorts (128B)
    __shared__ alignas(16) unsigned short As[6*4224];     // 50,688 B

    int tid = threadIdx.x;
    int wq  = tid >> 6;             // o-quarter
    int l   = tid & 63;
    int l15 = l & 15;
    int lq  = l >> 4;
    int o   = wq*16 + l15;

    const unsigned short* zrow = x2 + 167*64;   // guaranteed-zero row

    auto stage_plane = [&](int fp) {
        unsigned short* dstb = As + (fp % 6)*4224;
        #pragma unroll
        for (int it = 0; it < 3; ++it) {
            int idx = tid + it*256;             // plane = 528 16B-slots
            if (idx < 528) {
                int row = idx >> 3;             // tl 0..65
                int j   = idx & 7;
                int gt  = t0 - 1 + row;
                bool ok = (gt >= 0) && (gt < TT);
                int key = (row + fp) & 7;
                const unsigned short* src = ok
                    ? x2 + ((((size_t)b*TT + gt)*FP_ + fp)*64 + ((j ^ key)*8))
                    : zrow + j*8;
                __builtin_amdgcn_global_load_lds(
                    (const __attribute__((address_space(1))) void*)src,
                    (__attribute__((address_space(3))) void*)(dstb + (size_t)idx*8),
                    16, 0, 0);
            }
        }
    };

    // prologue: stage first 4 planes
    #pragma unroll
    for (int q = 0; q < 4; ++q) stage_plane(fb0*2 + q);
    __syncthreads();

    for (int n = 0; n < niter; ++n) {
        int f0 = (fb0 + n)*2;
        if (n + 1 < niter) {        // prefetch next iter's 2 planes (ring slots
            stage_plane(f0 + 4);    // hold f0-2,f0-1: retired after last barrier)
            stage_plane(f0 + 5);
        }

        f32x4 acc[2][4] = {};       // [u=f][mf]
        const unsigned short* wb = w2 + ((size_t)f0*COUT + o)*KTOT;
        // (fblk==80: u=1 weight reads run past w2 into x2 region: safe, discarded)

        int ps[4], kf[4];
        #pragma unroll
        for (int fl = 0; fl < 4; ++fl) {
            ps[fl] = ((f0 + fl) % 6) * 4224;
            kf[fl] = (f0 + fl) & 7;
        }

        bf16x8 bw0[6], bw1[6];
        auto ldw = [&](bf16x8 (&dst)[6], int p) {
            int is = p / 3, dm = p - (p/3)*3;
            int kb = is*32 + lq*8;
            #pragma unroll
            for (int dn = 0; dn < 3; ++dn)
                #pragma unroll
                for (int u = 0; u < 2; ++u)
                    dst[dn*2 + u] = *(const bf16x8*)&wb[(size_t)u*WST + (dm*3+dn)*64 + kb];
        };

        ldw(bw0, 0);
        #pragma unroll
        for (int p = 0; p < 6; ++p) {
            if (p < 5) { if (p & 1) ldw(bw0, p + 1); else ldw(bw1, p + 1); }
            int dm = p - (p/3)*3;
            int sbase = (p/3)*4 + lq;
            #pragma unroll
            for (int mf = 0; mf < 4; ++mf) {
                int tl = mf*16 + l15 + dm;
                bf16x8 a4[4];
                #pragma unroll
                for (int fl = 0; fl < 4; ++fl) {
                    int phys = sbase ^ ((tl + kf[fl]) & 7);
                    a4[fl] = *(const bf16x8*)&As[ps[fl] + tl*64 + phys*8];
                }
                #pragma unroll
                for (int dn = 0; dn < 3; ++dn)
                    #pragma unroll
                    for (int u = 0; u < 2; ++u)
                        acc[u][mf] = __builtin_amdgcn_mfma_f32_16x16x32_bf16(
                            a4[u + dn], (p & 1) ? bw1[dn*2 + u] : bw0[dn*2 + u],
                            acc[u][mf], 0, 0, 0);
            }
        }

        // epilogue: bias + bf16 -> tmp[b][f][t][o]
        #pragma unroll
        for (int u = 0; u < 2; ++u) {
            int fe = f0 + u;
            if (fe < FF) {
                float bv = bias[o*FF + fe];
                size_t tb = ((size_t)b*FF + fe)*TT + t0;
                #pragma unroll
                for (int mf = 0; mf < 4; ++mf)
                    #pragma unroll
                    for (int rr = 0; rr < 4; ++rr) {
                        int t = mf*16 + lq*4 + rr;
                        tmp[(tb + t)*COUT + o] = f2bf(acc[u][mf][rr] + bv);
                    }
            }
        }

        if (n + 1 < niter) __syncthreads();     // reads of iter n done; stage
                                                // (already in flight) may land
    }
}

// ---- finalize: tmp[b][f][t][o] bf16 -> out[b][o][t][f] f32 (bias already in) ----
__global__ __launch_bounds__(256) void finalize2(
    const unsigned short* __restrict__ tmp, float* __restrict__ out)
{
    int bx = blockIdx.x;            // 2048
    int b  = bx & 7;
    int s  = bx >> 3;
    int tb = s >> 1;
    int oh = s & 1;
    int t0 = tb * 4;
    int o0 = oh * 32;

    __shared__ unsigned short Ld[644*40];       // 51,520 B

    int tid = threadIdx.x;

    #pragma unroll
    for (int k = 0; k < 11; ++k) {
        int sl = tid + k*256;
        if (sl < 2576) {            // 161 f x 4 t x 4 j
            int f = sl >> 4;
            int r = sl & 15;
            int t = r >> 2;
            int j = r & 3;
            const unsigned short* src =
                tmp + (((size_t)b*FF + f)*TT + t0 + t)*COUT + o0 + j*8;
            int row = t*FF + f;
            *(u16x8*)&Ld[row*40 + ((j ^ (f & 3)) << 3)] = *(const u16x8*)src;
        }
    }
    __syncthreads();

    for (int ol = 0; ol < 32; ++ol) {
        int o = o0 + ol;
        float* op = out + (((size_t)b*COUT + o)*TT + t0)*FF;
        int jo = ol >> 3, o7 = ol & 7;
        #pragma unroll
        for (int k = 0; k < 3; ++k) {
            int r = tid + k*256;
            if (r < 4*FF) {
                int f = r % FF;
                op[r] = bf2f(Ld[r*40 + ((jo ^ (f & 3)) << 3) + o7]);
            }
        }
    }
}

// ---- small fallback: stages directly from f32 x; needs only w2 (12 MB ws) ----
__global__ __launch_bounds__(256) void conv_mfma(
    const float* __restrict__ x, const unsigned short* __restrict__ w2,
    const float* __restrict__ bias, float* __restrict__ out)
{
    int bx = blockIdx.x;
    int r  = bx & 7;
    int q  = bx >> 3;
    int fblk = q % 41;
    int g  = (q / 41) * 8 + r;
    int b  = g >> 3;
    int t0 = (g & 7) * 64;
    int f0 = fblk * 4;

    __shared__ unsigned short Bs[6][66][64];
    int tid = threadIdx.x;

    for (int i = 0; i < 64; i += 4) {
        #pragma unroll
        for (int pp = 0; pp < 2; ++pp) {
            int p = tid + pp*256;
            if (p < 396) {
                int tl = p / 6, fl = p % 6;
                int gt = t0 - 1 + tl;
                int gf = f0 - 1 + fl;
                bool ok = (gt >= 0) && (gt < TT) && (gf >= 0) && (gf < FF);
                const float* xp = x + (((size_t)(b*CIN + i)*TT + gt)*FF + gf);
                float v0 = ok ? xp[0]       : 0.f;
                float v1 = ok ? xp[TFSTR]   : 0.f;
                float v2 = ok ? xp[2*TFSTR] : 0.f;
                float v3 = ok ? xp[3*TFSTR] : 0.f;
                int isw = i ^ (((tl + fl) & 7) << 3);
                ushort4 pk;
                pk.x = f2bf(v0); pk.y = f2bf(v1); pk.z = f2bf(v2); pk.w = f2bf(v3);
                *reinterpret_cast<ushort4*>(&Bs[fl][tl][isw]) = pk;
            }
        }
    }
    __syncthreads();

    int wv = tid >> 6;
    int l  = tid & 63;
    int f  = f0 + wv;
    if (f >= FF) return;

    int l15 = l & 15;
    int lq  = l >> 4;
    f32x4 acc[4][4] = {};
    const unsigned short* wb = w2 + (size_t)f * (COUT * KTOT);

    #pragma unroll
    for (int dm = 0; dm < 3; ++dm)
    #pragma unroll
    for (int dn = 0; dn < 3; ++dn) {
        int fl = wv + dn;
        int kq = (dm*3 + dn) * 64;
        #pragma unroll
        for (int is = 0; is < 2; ++is) {
            int i0 = is*32 + lq*8;
            bf16x8 a[4];
            #pragma unroll
            for (int mf = 0; mf < 4; ++mf) {
                int tl  = mf*16 + l15 + dm;
                int isw = i0 ^ (((tl + fl) & 7) << 3);
                a[mf] = *(const bf16x8*)&Bs[fl][tl][isw];
            }
            int kb = kq + i0;
            #pragma unroll
            for (int nf = 0; nf < 4; ++nf) {
                bf16x8 bfr = *(const bf16x8*)&wb[(size_t)(nf*16 + l15) * KTOT + kb];
                #pragma unroll
                for (int mf = 0; mf < 4; ++mf)
                    acc[mf][nf] = __builtin_amdgcn_mfma_f32_16x16x32_bf16(
                        a[mf], bfr, acc[mf][nf], 0, 0, 0);
            }
        }
    }

    #pragma unroll
    for (int nf = 0; nf < 4; ++nf) {
        int o = nf*16 + l15;
        float bv = bias[o*FF + f];
        size_t obase = (((size_t)b*COUT + o)*TT + t0 + lq*4)*FF + f;
        #pragma unroll
        for (int mf = 0; mf < 4; ++mf)
            #pragma unroll
            for (int rr = 0; rr < 4; ++rr)
                out[obase + (size_t)(mf*16 + rr)*FF] = acc[mf][nf][rr] + bv;
    }
}

extern "C" void kernel_launch(void* const* d_in, const int* in_sizes, int n_in,
                              void* d_out, int out_size, void* d_ws, size_t ws_size,
                              hipStream_t stream)
{
    (void)in_sizes; (void)n_in; (void)out_size;
    const float* x    = (const float*)d_in[0];
    const float* k    = (const float*)d_in[1];
    const float* bias = (const float*)d_in[2];
    float* out = (float*)d_out;
    unsigned short* w2  = (unsigned short*)d_ws;
    unsigned short* x2  = (unsigned short*)((char*)d_ws + W2_BYTES);
    unsigned short* tmp = (unsigned short*)((char*)d_ws + W2_BYTES + X2_BYTES);

    bool big2 = (ws_size >= W2_BYTES + X2_BYTES + TMP_BYTES);

    prep_fused<<<big2 ? (PW_BLOCKS + 8*TT) : PW_BLOCKS, 256, 0, stream>>>(k, w2, x, x2);

    if (big2) {
        conv_mfma11<<<2048, 256, 0, stream>>>(x2, w2, bias, tmp);  // 3 blk/CU
        finalize2<<<2048, 256, 0, stream>>>(tmp, out);
    } else {
        conv_mfma<<<8*41*8, 256, 0, stream>>>(x, w2, bias, out);   // fallback
    }
}